// Round 8
// baseline (268.274 us; speedup 1.0000x reference)
//
#include <hip/hip_runtime.h>
#include <hip/hip_bf16.h>
#include <stdint.h>

// TemporalAttention: x[B,T,C] -> qkv proj -> causal MHA -> out proj.
// B=4 T=2048 C=1024 H=16 D=64. Inputs fp32, output fp32; internal bf16 MFMA.
//
// R13 post-mortem: counted-vmcnt gemm +4% only (2-barrier structure caps
// ~675TF, matches m230); launch overhead ~1.5us/launch (merge gave ~3us,
// not 20) -> board = gemm1 76.5 + attn 76.5. R14 (attn only): delete the
// P LDS roundtrip (2 hard lgkm drains + 6 LDS ops/job) -> 8-shuffle
// in-register P redistribution (T12-analog; index algebra lane-verified);
// frees sP (LDS 40960->32768); s_setprio(1) around QK/PV MFMA clusters
// (m191: attn +4-7%). gemm untouched; next lever there = 8-phase port.

using bf16 = __hip_bfloat16;
typedef __attribute__((ext_vector_type(8))) __bf16 bf16x8;
typedef __attribute__((ext_vector_type(8))) unsigned short u16x8;
typedef __attribute__((ext_vector_type(4))) unsigned short u16x4;
typedef __attribute__((ext_vector_type(4))) unsigned int u32x4;
typedef __attribute__((ext_vector_type(4))) float f32x4;
typedef unsigned short ushort_t;

#define MFMA16(a, b, c) __builtin_amdgcn_mfma_f32_16x16x32_bf16((a), (b), (c), 0, 0, 0)

__device__ __forceinline__ bf16x8 ld_frag(const ushort_t* p) {
  const u16x8 u = *(const u16x8*)p;
  return __builtin_bit_cast(bf16x8, u);
}

__device__ __forceinline__ ushort_t f2bf(float f) {
  return __builtin_bit_cast(ushort_t, __float2bfloat16(f));
}

// async global->LDS, 16B/lane; lds base wave-uniform, lane l -> base+l*16.
__device__ __forceinline__ void gl2lds16(const void* g, void* lds) {
  __builtin_amdgcn_global_load_lds((const __attribute__((address_space(1))) void*)g,
                                   (__attribute__((address_space(3))) void*)lds,
                                   16, 0, 0);
}

// ---------------------------------------------------------------------------
// Dtype detector (hedge; fp32 established). flag=1 -> fp32.
// ---------------------------------------------------------------------------
__global__ void detect_dtype(const ushort_t* __restrict__ x, int* __restrict__ flag) {
  __shared__ int red[256];
  const int tid = threadIdx.x;
  int cnt = 0;
  for (int i = tid; i < 4096; i += 256) {
    const int e = (x[i] & 0x7FFF) >> 7;
    cnt += (e >= 117 && e <= 133) ? 1 : 0;
  }
  red[tid] = cnt;
  __syncthreads();
  for (int s = 128; s > 0; s >>= 1) {
    if (tid < s) red[tid] += red[tid + s];
    __syncthreads();
  }
  if (tid == 0) *flag = (red[0] < 3072) ? 1 : 0;
}

// ---------------------------------------------------------------------------
// Merged fp32->bf16 conversion for x / w_qkv / w_out in one launch.
// Block-range dispatch: [0,4096) -> x (8.39M), [4096,5632) -> w_qkv (3.15M),
// [5632,6144) -> w_out (1.05M). 2048 elems/block.
// ---------------------------------------------------------------------------
__global__ void cvt_all(const void* __restrict__ x, const void* __restrict__ wq,
                        const void* __restrict__ wo, ushort_t* __restrict__ xo,
                        ushort_t* __restrict__ wqo, ushort_t* __restrict__ woo,
                        const int* __restrict__ flag) {
  const int b = blockIdx.x;
  const void* src;
  ushort_t* dst;
  int i;
  if (b < 4096) {
    src = x; dst = xo; i = b * 2048 + threadIdx.x * 8;
  } else if (b < 5632) {
    src = wq; dst = wqo; i = (b - 4096) * 2048 + threadIdx.x * 8;
  } else {
    src = wo; dst = woo; i = (b - 5632) * 2048 + threadIdx.x * 8;
  }
  if (*flag) {
    const float* p = (const float*)src + i;
    const float4 f0 = *(const float4*)p;
    const float4 f1 = *(const float4*)(p + 4);
    u16x8 u;
    u[0] = f2bf(f0.x); u[1] = f2bf(f0.y); u[2] = f2bf(f0.z); u[3] = f2bf(f0.w);
    u[4] = f2bf(f1.x); u[5] = f2bf(f1.y); u[6] = f2bf(f1.z); u[7] = f2bf(f1.w);
    *(u16x8*)(dst + i) = u;
  } else {
    *(u16x8*)(dst + i) = *(const u16x8*)((const ushort_t*)src + i);
  }
}

// ---------------------------------------------------------------------------
// NT GEMM: C[M,N] = A[M,K]*B[N,K]^T. 128x128 tile, 4 waves 2x2, BK=32,
// 16x16x32 bf16 MFMA. R13 triple-buffered counted-vmcnt schedule
// (unchanged). EPI==0: fp32 store. EPI==1: scatter q/k, V^T.
// ---------------------------------------------------------------------------
template <int EPI>
__global__ __launch_bounds__(256, 2)
void gemm_nt(const ushort_t* __restrict__ A, const void* __restrict__ Bw,
             const int* __restrict__ flag, int bExt,
             float* __restrict__ C0, ushort_t* __restrict__ Qo,
             ushort_t* __restrict__ Ko, ushort_t* __restrict__ Vt,
             int M, int N, int Kd) {
  __shared__ ushort_t sA[3][128 * 32];
  __shared__ ushort_t sB[3][128 * 32];
  const int tid = threadIdx.x;
  const int wave = tid >> 6, lane = tid & 63;
  const int quad = lane >> 4, l16 = lane & 15;
  const int wm = wave >> 1, wn = wave & 1;
  const long m0 = (long)blockIdx.y * 128;
  const long n0 = (long)blockIdx.x * 128;
  const int bF = bExt ? *flag : 0;

  f32x4 acc[4][4];
#pragma unroll
  for (int i = 0; i < 4; ++i)
#pragma unroll
    for (int j = 0; j < 4; ++j) acc[i][j] = (f32x4){0.f, 0.f, 0.f, 0.f};

  const int nt = Kd >> 5;  // K-steps of 32

  auto stageA = [&](int buf, int k0) {
#pragma unroll
    for (int j = 0; j < 2; ++j) {
      const int chunk = wave * 2 + j;     // wave-uniform LDS base
      const int idx = chunk * 64 + lane;  // 0..511: 16B chunk per lane
      const int r = idx >> 2, c = idx & 3;
      gl2lds16(A + (m0 + r) * (long)Kd + k0 + c * 8,
               (char*)&sA[buf][0] + chunk * 1024);
    }
  };
  auto stageB = [&](int buf, int k0) {
    if (!bF) {
#pragma unroll
      for (int j = 0; j < 2; ++j) {
        const int chunk = wave * 2 + j;
        const int idx = chunk * 64 + lane;
        const int r = idx >> 2, c = idx & 3;
        gl2lds16((const ushort_t*)Bw + (n0 + r) * (long)Kd + k0 + c * 8,
                 (char*)&sB[buf][0] + chunk * 1024);
      }
    } else {
#pragma unroll
      for (int t2 = 0; t2 < 2; ++t2) {
        const int idx = t2 * 256 + tid;
        const int r = idx >> 2, c = idx & 3;
        const float* p = (const float*)Bw + (n0 + r) * (long)Kd + k0 + c * 8;
        const float4 f0 = *(const float4*)p;
        const float4 f1 = *(const float4*)(p + 4);
        u16x8 u;
        u[0] = f2bf(f0.x); u[1] = f2bf(f0.y); u[2] = f2bf(f0.z); u[3] = f2bf(f0.w);
        u[4] = f2bf(f1.x); u[5] = f2bf(f1.y); u[6] = f2bf(f1.z); u[7] = f2bf(f1.w);
        *(u16x8*)&sB[buf][r * 32 + c * 8] = u;
      }
    }
  };

  // prologue: stage tiles 0 and 1
  stageA(0, 0);
  stageB(0, 0);
  if (nt > 1) {
    stageA(1, 32);
    stageB(1, 32);
  }

  for (int t = 0; t < nt; ++t) {
    if (!bF && t + 1 < nt) {
      // drain tile t's 4 loads; tile t+1's 4 stay in flight across barrier
      asm volatile("s_waitcnt vmcnt(4) lgkmcnt(0)\n\ts_barrier" ::: "memory");
    } else {
      asm volatile("s_waitcnt vmcnt(0) lgkmcnt(0)\n\ts_barrier" ::: "memory");
    }
    if (t + 2 < nt) {  // issue tile t+2; flies for TWO full iterations
      stageA((t + 2) % 3, (t + 2) << 5);
      stageB((t + 2) % 3, (t + 2) << 5);
    }
    const ushort_t* cA = &sA[t % 3][0];
    const ushort_t* cB = &sB[t % 3][0];
    bf16x8 af[4], bfr[4];
#pragma unroll
    for (int i = 0; i < 4; ++i) {
      const int r = wm * 64 + i * 16 + l16;
      af[i] = ld_frag(&cA[r * 32 + quad * 8]);
    }
#pragma unroll
    for (int i = 0; i < 4; ++i) {
      const int r = wn * 64 + i * 16 + l16;
      bfr[i] = ld_frag(&cB[r * 32 + quad * 8]);
    }
#pragma unroll
    for (int i = 0; i < 4; ++i)
#pragma unroll
      for (int j = 0; j < 4; ++j) acc[i][j] = MFMA16(af[i], bfr[j], acc[i][j]);
  }

  // epilogue: C/D layout col=lane&15, row=quad*4+reg (m89-verified)
#pragma unroll
  for (int i = 0; i < 4; ++i) {
#pragma unroll
    for (int j = 0; j < 4; ++j) {
      if (EPI == 0) {
#pragma unroll
        for (int reg = 0; reg < 4; ++reg) {
          const long m = m0 + wm * 64 + i * 16 + quad * 4 + reg;
          const long n = n0 + wn * 64 + j * 16 + l16;
          C0[m * N + n] = acc[i][j][reg];
        }
      } else {
        const long n = n0 + wn * 64 + j * 16 + l16;
        const int which = (int)(n >> 10);  // block-uniform
        const int h = (int)((n >> 6) & 15);
        const int d = (int)(n & 63);
        const long mbase = m0 + wm * 64 + i * 16 + quad * 4;
        const long b = mbase >> 11;
        const long tb = mbase & 2047;
        if (which == 2) {
          u16x4 pk;
#pragma unroll
          for (int reg = 0; reg < 4; ++reg) pk[reg] = f2bf(acc[i][j][reg]);
          *(u16x4*)&Vt[((b * 16 + h) * 64 + d) * 2048 + tb] = pk;
        } else {
          ushort_t* dst = (which == 0) ? Qo : Ko;
#pragma unroll
          for (int reg = 0; reg < 4; ++reg)
            dst[((b * 16 + h) * 2048 + tb + reg) * 64 + d] = f2bf(acc[i][j][reg]);
        }
      }
    }
  }
}

// ---------------------------------------------------------------------------
// Flash attention (causal), S^T/O^T formulation. R14: P LDS roundtrip
// replaced by 8-shuffle in-register redistribution. Derivation:
// s[nt][reg] = P[key=nt*16+quad*4+reg][q=l16]; PV B-frag needs
// P[kk*32+quad*8+e][l16], e=0..7 (u32[j] = pair e=2j,2j+1). With
// b0=quad&1, b1=quad>>1, c=j>>1, h=j&1: needed value = pk_h[2kk+b1]
// from src lane quad_s=2*b0+c. Shuffle S1: src=(2b0+b1), src-side value
// pk_h[2kk + (own quad&1)] -> delivers pk_h[2kk+b1], fills slot j=2*b1+h.
// S2: src=(2b0+1-b1), value pk_h[2kk+1-(own quad&1)] -> same value,
// fills slot j=2*(1-b1)+h. Lane-verified on concrete cases.
// sP deleted (LDS 32KB). setprio(1) around MFMA clusters (T5, m191).
// ---------------------------------------------------------------------------

// softmax over S^T tile held in s[4] (keys = kb+nt*16+reg, q col = l16).
// Mutates s to P values; updates m_i, l_i; rescales oacc on max growth.
__device__ __forceinline__ void softmax_tile(f32x4* s, int kb, int qg, bool need_mask,
                                             float& m_i, float& l_i, f32x4* oacc) {
  float rmax = -1e30f;
  if (need_mask) {  // diagonal tiles only (wave-uniform)
#pragma unroll
    for (int nt = 0; nt < 4; ++nt) {
#pragma unroll
      for (int reg = 0; reg < 4; ++reg) {
        float v = s[nt][reg];
        if (kb + nt * 16 + reg > qg) v = -1e30f;
        s[nt][reg] = v;
        rmax = fmaxf(rmax, v);
      }
    }
  } else {
#pragma unroll
    for (int nt = 0; nt < 4; ++nt) {
#pragma unroll
      for (int reg = 0; reg < 4; ++reg) rmax = fmaxf(rmax, s[nt][reg]);
    }
  }
  rmax = fmaxf(rmax, __shfl_xor(rmax, 16, 64));
  rmax = fmaxf(rmax, __shfl_xor(rmax, 32, 64));
  float mnew = fmaxf(m_i, rmax);
  if (__all(rmax - m_i <= 5.5f)) {
    mnew = m_i;  // defer-max: P bounded by e^5.5 ~ 245, f32 accum tolerates
  } else {
    const float alpha = __expf(m_i - mnew);
    l_i *= alpha;
#pragma unroll
    for (int dt = 0; dt < 4; ++dt) oacc[dt] *= alpha;
    m_i = mnew;
  }
  float rs = 0.f;
#pragma unroll
  for (int nt = 0; nt < 4; ++nt) {
#pragma unroll
    for (int reg = 0; reg < 4; ++reg) {
      const float p = __expf(s[nt][reg] - mnew);
      s[nt][reg] = p;
      rs += p;
    }
  }
  rs += __shfl_xor(rs, 16, 64);
  rs += __shfl_xor(rs, 32, 64);
  l_i += rs;
}

// one q-tile job: QK^T -> softmax -> in-reg P redistribution -> PV.
__device__ __forceinline__ void attn_job(const bf16x8 qf[2], const ushort_t* sKc,
                                         const ushort_t* sVc,
                                         int kv, int qg, bool need_mask,
                                         int quad, int l8, int l16,
                                         float& m_i, float& l_i, f32x4* oacc) {
  const f32x4 ZERO4 = {0.f, 0.f, 0.f, 0.f};
  const int off0 = ((quad ^ l8) << 3);        // col16=quad   (kk=0), swizzled
  const int off1 = (((quad + 4) ^ l8) << 3);  // col16=quad+4 (kk=1), swizzled
  f32x4 s[4];
  __builtin_amdgcn_s_setprio(1);
#pragma unroll
  for (int nt = 0; nt < 4; ++nt) {
    const ushort_t* krow = sKc + (nt * 16 + l16) * 64;
    s[nt] = MFMA16(ld_frag(krow + off0), qf[0], ZERO4);
    s[nt] = MFMA16(ld_frag(krow + off1), qf[1], s[nt]);
  }
  __builtin_amdgcn_s_setprio(0);
  softmax_tile(s, kv * 64 + quad * 4, qg, need_mask, m_i, l_i, oacc);

  // pack P quad-columns into u32 bf16-pairs
  uint32_t pk01[4], pk23[4];
#pragma unroll
  for (int nt = 0; nt < 4; ++nt) {
    pk01[nt] = (uint32_t)f2bf(s[nt][0]) | ((uint32_t)f2bf(s[nt][1]) << 16);
    pk23[nt] = (uint32_t)f2bf(s[nt][2]) | ((uint32_t)f2bf(s[nt][3]) << 16);
  }
  const int b0 = quad & 1, b1 = quad >> 1;
  const int src1 = ((b0 << 1) + b1) * 16 + l16;
  const int src2 = ((b0 << 1) + (1 - b1)) * 16 + l16;
  bf16x8 pf[2];
#pragma unroll
  for (int kk = 0; kk < 2; ++kk) {
    uint32_t r[4];
#pragma unroll
    for (int h = 0; h < 2; ++h) {
      // source-side value select by OWN c = quad&1 (evaluated in src lane)
      const uint32_t v1 = b0 ? (h ? pk23[2 * kk + 1] : pk01[2 * kk + 1])
                             : (h ? pk23[2 * kk + 0] : pk01[2 * kk + 0]);
      const uint32_t v2 = b0 ? (h ? pk23[2 * kk + 0] : pk01[2 * kk + 0])
                             : (h ? pk23[2 * kk + 1] : pk01[2 * kk + 1]);
      const uint32_t g1 = (uint32_t)__shfl((int)v1, src1, 64);
      const uint32_t g2 = (uint32_t)__shfl((int)v2, src2, 64);
      r[h] = b1 ? g2 : g1;      // slot j=h   (src c=0)
      r[2 + h] = b1 ? g1 : g2;  // slot j=2+h (src c=1)
    }
    const u32x4 rv = {r[0], r[1], r[2], r[3]};
    pf[kk] = __builtin_bit_cast(bf16x8, rv);
  }
  __builtin_amdgcn_s_setprio(1);
#pragma unroll
  for (int dt = 0; dt < 4; ++dt) {
    const ushort_t* vrow = sVc + (dt * 16 + l16) * 64;
    oacc[dt] = MFMA16(ld_frag(vrow + off0), pf[0], oacc[dt]);
    oacc[dt] = MFMA16(ld_frag(vrow + off1), pf[1], oacc[dt]);
  }
  __builtin_amdgcn_s_setprio(0);
}

__global__ __launch_bounds__(256, 4)
void attn_causal(const ushort_t* __restrict__ Qg, const ushort_t* __restrict__ Kg,
                 const ushort_t* __restrict__ Vt, ushort_t* __restrict__ Yg) {
  __shared__ ushort_t sK[2][64 * 64];  // swizzled-linear tiles, dbuf
  __shared__ ushort_t sV[2][64 * 64];
  const int tid = threadIdx.x;
  const int wave = tid >> 6, lane = tid & 63;
  const int quad = lane >> 4, l16 = lane & 15, l8 = lane & 7;
  const f32x4 ZERO4 = {0.f, 0.f, 0.f, 0.f};
  // XCD-aware bijective remap: XCD k owns bh in [8k,8k+8) -> 4MB KV = L2.
  const int lin = blockIdx.y * 16 + blockIdx.x;
  const int logical = (lin & 7) * 128 + (lin >> 3);
  const int qx = logical & 15, bh = logical >> 4;
  const int qtA = qx, qtB = 31 - qx;
  const size_t base = (size_t)bh * 2048 * 64;

  // staging geometry: chunk = 8 rows x 128B; lane l -> row chunk*8+(l>>3),
  // LDS bytes (l&7)*16. Pre-swizzled SOURCE col so swizzled reads match:
  // src col8 = (l&7) ^ ((l>>3)&7).
  const int srow = lane >> 3;                    // row within chunk
  const int scol = ((lane & 7) ^ srow) << 3;     // src col in elems (x8)

  // Q fragments direct from global, pre-scaled by 1/sqrt(64)=0.125 (exact)
  bf16x8 qfA[2], qfB[2];
#pragma unroll
  for (int tile = 0; tile < 2; ++tile) {
    const int qt = tile ? qtB : qtA;
    const size_t qrow = base + (size_t)(qt * 64 + wave * 16 + l16) * 64;
#pragma unroll
    for (int kk = 0; kk < 2; ++kk) {
      const u16x8 u = *(const u16x8*)(Qg + qrow + (kk * 4 + quad) * 8);
      u16x8 w;
#pragma unroll
      for (int e = 0; e < 8; ++e)
        w[e] = f2bf(__bfloat162float(__builtin_bit_cast(bf16, (ushort_t)u[e])) * 0.125f);
      const bf16x8 f = __builtin_bit_cast(bf16x8, w);
      if (tile) qfB[kk] = f; else qfA[kk] = f;
    }
  }

  float mA = -1e30f, lA = 0.f, mB = -1e30f, lB = 0.f;
  f32x4 oA[4], oB[4];
#pragma unroll
  for (int dt = 0; dt < 4; ++dt) {
    oA[dt] = ZERO4;
    oB[dt] = ZERO4;
  }
  const int qgA = qtA * 64 + wave * 16 + l16;
  const int qgB = qtB * 64 + wave * 16 + l16;
  const int qmA = qtA * 64 + wave * 16;  // wave-min q row (mask hoist)
  const int qmB = qtB * 64 + wave * 16;

  // prologue: stage tile 0 into buf 0 (async; drained by first barrier)
#pragma unroll
  for (int j = 0; j < 2; ++j) {
    const int chunk = wave * 2 + j;  // wave-uniform
    gl2lds16(Kg + base + (size_t)(chunk * 8 + srow) * 64 + scol,
             (char*)&sK[0][0] + chunk * 1024);
    gl2lds16(Vt + base + (size_t)(chunk * 8 + srow) * 2048 + scol,
             (char*)&sV[0][0] + chunk * 1024);
  }

  for (int kv = 0; kv <= qtB; ++kv) {
    const int cur = kv & 1;
    __syncthreads();  // drains vmcnt: buf[cur] filled; all waves past reads of buf[cur^1]
    if (kv < qtB) {   // async-stage tile kv+1 into the other buffer
      const int kn = kv + 1;
#pragma unroll
      for (int j = 0; j < 2; ++j) {
        const int chunk = wave * 2 + j;
        gl2lds16(Kg + base + (size_t)(kn * 64 + chunk * 8 + srow) * 64 + scol,
                 (char*)&sK[cur ^ 1][0] + chunk * 1024);
        gl2lds16(Vt + base + (size_t)(chunk * 8 + srow) * 2048 + kn * 64 + scol,
                 (char*)&sV[cur ^ 1][0] + chunk * 1024);
      }
    }
    const ushort_t* sKc = &sK[cur][0];
    const ushort_t* sVc = &sV[cur][0];
    attn_job(qfB, sKc, sVc, kv, qgB, kv * 64 + 63 > qmB, quad, l8, l16, mB, lB, oB);
    if (kv <= qtA)
      attn_job(qfA, sKc, sVc, kv, qgA, kv * 64 + 63 > qmA, quad, l8, l16, mA, lA, oA);
  }

  const int b = bh >> 4, h = bh & 15;
#pragma unroll
  for (int tile = 0; tile < 2; ++tile) {
    const int qt = tile ? qtB : qtA;
    const float linv = 1.f / (tile ? lB : lA);
    const f32x4* o = tile ? oB : oA;
    const int t = qt * 64 + wave * 16 + l16;
#pragma unroll
    for (int dt = 0; dt < 4; ++dt) {
      u16x4 pk;
#pragma unroll
      for (int reg = 0; reg < 4; ++reg) pk[reg] = f2bf(o[dt][reg] * linv);
      *(u16x4*)&Yg[(((size_t)b * 2048 + t) * 16 + h) * 64 + dt * 16 + quad * 4] = pk;
    }
  }
}

extern "C" void kernel_launch(void* const* d_in, const int* in_sizes, int n_in,
                              void* d_out, int out_size, void* d_ws, size_t ws_size,
                              hipStream_t stream) {
  const void* x = d_in[0];      // [4,2048,1024] fp32
  const void* w_qkv = d_in[1];  // [3072,1024] fp32
  const void* w_out = d_in[2];  // [1024,1024] fp32
  float* out = (float*)d_out;   // [4,2048,1024] fp32

  const size_t per = (size_t)4 * 16 * 2048 * 64;  // 8.39M elems
  const size_t nwqkv = (size_t)3072 * 1024;       // 3.15M
  const size_t nwout = (size_t)1024 * 1024;       // 1.05M
  ushort_t* qws = (ushort_t*)d_ws;   // [B,H,T,D]
  ushort_t* kws = qws + per;         // [B,H,T,D]
  ushort_t* vTws = kws + per;        // [B,H,D,T]
  ushort_t* xyws = vTws + per;       // xbf for gemm1, then y [B,T,H,D]
  ushort_t* wqkvb = xyws + per;      // bf16 w_qkv
  ushort_t* woutb = wqkvb + nwqkv;   // bf16 w_out
  int* flag = (int*)(woutb + nwout);
  const size_t need = (size_t)(4 * per + nwqkv + nwout) * 2 + 16;
  const bool pre = ws_size >= need;  // stable across calls (graph-safe)
  (void)in_sizes; (void)n_in; (void)out_size;

  dim3 blk(256);
  if (!pre) flag = (int*)(xyws + per);
  detect_dtype<<<1, 256, 0, stream>>>((const ushort_t*)x, flag);
  if (pre) {
    cvt_all<<<6144, 256, 0, stream>>>(x, w_qkv, w_out, xyws, wqkvb, woutb, flag);
    gemm_nt<1><<<dim3(24, 64), blk, 0, stream>>>(xyws, wqkvb, flag, 0, nullptr,
                                                 qws, kws, vTws, 8192, 3072, 1024);
    attn_causal<<<dim3(16, 64), blk, 0, stream>>>(qws, kws, vTws, xyws);
    gemm_nt<0><<<dim3(8, 64), blk, 0, stream>>>(xyws, woutb, flag, 0, out,
                                                nullptr, nullptr, nullptr,
                                                8192, 1024, 1024);
  } else {
    cvt_all<<<4096, 256, 0, stream>>>(x, nullptr, nullptr, xyws, nullptr, nullptr, flag);
    gemm_nt<1><<<dim3(24, 64), blk, 0, stream>>>(xyws, w_qkv, flag, 1, nullptr,
                                                 qws, kws, vTws, 8192, 3072, 1024);
    attn_causal<<<dim3(16, 64), blk, 0, stream>>>(qws, kws, vTws, xyws);
    gemm_nt<0><<<dim3(8, 64), blk, 0, stream>>>(xyws, w_out, flag, 1, out,
                                                nullptr, nullptr, nullptr,
                                                8192, 1024, 1024);
  }
}

// Round 9
// 246.147 us; speedup vs baseline: 1.0899x; 1.0899x over previous
//
#include <hip/hip_runtime.h>
#include <hip/hip_bf16.h>
#include <stdint.h>

// TemporalAttention: x[B,T,C] -> qkv proj -> causal MHA -> out proj.
// B=4 T=2048 C=1024 H=16 D=64. Inputs fp32, output fp32; internal bf16 MFMA.
//
// R14 post-mortem: shuffle-P regressed attn 76.5->84 (shfl = ds_bpermute,
// still LDS pipe, + cndmask soup; VALU 38->51%). R15: (a) revert attn to
// R13-best (P LDS roundtrip, no setprio); (b) gemm EPI=1 V^T epilogue was
// an 8B/4KB-stride scatter (64 txn/instr) -> LDS transpose (reuse staging
// LDS post-loop, stride 136) + coalesced u16x8 stores along tb;
// (c) pre path drops detect_dtype launch — cvt_all self-detects per wave
// from the tensor's 64-ushort prefix (same 75% rule).

using bf16 = __hip_bfloat16;
typedef __attribute__((ext_vector_type(8))) __bf16 bf16x8;
typedef __attribute__((ext_vector_type(8))) unsigned short u16x8;
typedef __attribute__((ext_vector_type(4))) unsigned short u16x4;
typedef __attribute__((ext_vector_type(4))) float f32x4;
typedef unsigned short ushort_t;

#define MFMA16(a, b, c) __builtin_amdgcn_mfma_f32_16x16x32_bf16((a), (b), (c), 0, 0, 0)

__device__ __forceinline__ bf16x8 ld_frag(const ushort_t* p) {
  const u16x8 u = *(const u16x8*)p;
  return __builtin_bit_cast(bf16x8, u);
}

__device__ __forceinline__ ushort_t f2bf(float f) {
  return __builtin_bit_cast(ushort_t, __float2bfloat16(f));
}

// async global->LDS, 16B/lane; lds base wave-uniform, lane l -> base+l*16.
__device__ __forceinline__ void gl2lds16(const void* g, void* lds) {
  __builtin_amdgcn_global_load_lds((const __attribute__((address_space(1))) void*)g,
                                   (__attribute__((address_space(3))) void*)lds,
                                   16, 0, 0);
}

// ---------------------------------------------------------------------------
// Dtype detector (non-pre path only; feeds gemm bF flag). flag=1 -> fp32.
// ---------------------------------------------------------------------------
__global__ void detect_dtype(const ushort_t* __restrict__ x, int* __restrict__ flag) {
  __shared__ int red[256];
  const int tid = threadIdx.x;
  int cnt = 0;
  for (int i = tid; i < 4096; i += 256) {
    const int e = (x[i] & 0x7FFF) >> 7;
    cnt += (e >= 117 && e <= 133) ? 1 : 0;
  }
  red[tid] = cnt;
  __syncthreads();
  for (int s = 128; s > 0; s >>= 1) {
    if (tid < s) red[tid] += red[tid + s];
    __syncthreads();
  }
  if (tid == 0) *flag = (red[0] < 3072) ? 1 : 0;
}

// ---------------------------------------------------------------------------
// Merged fp32->bf16 conversion for x / w_qkv / w_out in one launch, with
// per-wave dtype self-detection from the tensor's 64-ushort prefix
// (bf16-exponent in [117,133] for >=75% of samples -> already bf16).
// Block-range dispatch: [0,4096) x, [4096,5632) w_qkv, [5632,6144) w_out.
// ---------------------------------------------------------------------------
__global__ void cvt_all(const void* __restrict__ x, const void* __restrict__ wq,
                        const void* __restrict__ wo, ushort_t* __restrict__ xo,
                        ushort_t* __restrict__ wqo, ushort_t* __restrict__ woo) {
  const int b = blockIdx.x;
  const void* src;
  ushort_t* dst;
  int i;
  if (b < 4096) {
    src = x; dst = xo; i = b * 2048 + threadIdx.x * 8;
  } else if (b < 5632) {
    src = wq; dst = wqo; i = (b - 4096) * 2048 + threadIdx.x * 8;
  } else {
    src = wo; dst = woo; i = (b - 5632) * 2048 + threadIdx.x * 8;
  }
  const int lane = threadIdx.x & 63;
  const int e = (((const ushort_t*)src)[lane] & 0x7FFF) >> 7;
  const int cnt = __popcll(__ballot(e >= 117 && e <= 133));
  if (cnt < 48) {  // fp32 input
    const float* p = (const float*)src + i;
    const float4 f0 = *(const float4*)p;
    const float4 f1 = *(const float4*)(p + 4);
    u16x8 u;
    u[0] = f2bf(f0.x); u[1] = f2bf(f0.y); u[2] = f2bf(f0.z); u[3] = f2bf(f0.w);
    u[4] = f2bf(f1.x); u[5] = f2bf(f1.y); u[6] = f2bf(f1.z); u[7] = f2bf(f1.w);
    *(u16x8*)(dst + i) = u;
  } else {
    *(u16x8*)(dst + i) = *(const u16x8*)((const ushort_t*)src + i);
  }
}

// ---------------------------------------------------------------------------
// NT GEMM: C[M,N] = A[M,K]*B[N,K]^T. 128x128 tile, 4 waves 2x2, BK=32,
// 16x16x32 bf16 MFMA. R13 triple-buffered counted-vmcnt schedule.
// R15: EPI==1 V-region (which==2) epilogue transposes through the staging
// LDS (free after K-loop; stride 136 ushort for 16B alignment + bank
// spread) -> coalesced u16x8 stores along tb (was 8B/4KB-stride scatter).
// ---------------------------------------------------------------------------
template <int EPI>
__global__ __launch_bounds__(256, 2)
void gemm_nt(const ushort_t* __restrict__ A, const void* __restrict__ Bw,
             const int* __restrict__ flag, int bExt,
             float* __restrict__ C0, ushort_t* __restrict__ Qo,
             ushort_t* __restrict__ Ko, ushort_t* __restrict__ Vt,
             int M, int N, int Kd) {
  __shared__ ushort_t smem[24576];  // sA[3][4096] | sB[3][4096]; reused by epilogue
  const int tid = threadIdx.x;
  const int wave = tid >> 6, lane = tid & 63;
  const int quad = lane >> 4, l16 = lane & 15;
  const int wm = wave >> 1, wn = wave & 1;
  const long m0 = (long)blockIdx.y * 128;
  const long n0 = (long)blockIdx.x * 128;
  const int bF = bExt ? *flag : 0;

  f32x4 acc[4][4];
#pragma unroll
  for (int i = 0; i < 4; ++i)
#pragma unroll
    for (int j = 0; j < 4; ++j) acc[i][j] = (f32x4){0.f, 0.f, 0.f, 0.f};

  const int nt = Kd >> 5;  // K-steps of 32

  auto stageA = [&](int buf, int k0) {
#pragma unroll
    for (int j = 0; j < 2; ++j) {
      const int chunk = wave * 2 + j;     // wave-uniform LDS base
      const int idx = chunk * 64 + lane;  // 0..511: 16B chunk per lane
      const int r = idx >> 2, c = idx & 3;
      gl2lds16(A + (m0 + r) * (long)Kd + k0 + c * 8,
               (char*)(smem + buf * 4096) + chunk * 1024);
    }
  };
  auto stageB = [&](int buf, int k0) {
    if (!bF) {
#pragma unroll
      for (int j = 0; j < 2; ++j) {
        const int chunk = wave * 2 + j;
        const int idx = chunk * 64 + lane;
        const int r = idx >> 2, c = idx & 3;
        gl2lds16((const ushort_t*)Bw + (n0 + r) * (long)Kd + k0 + c * 8,
                 (char*)(smem + 12288 + buf * 4096) + chunk * 1024);
      }
    } else {
#pragma unroll
      for (int t2 = 0; t2 < 2; ++t2) {
        const int idx = t2 * 256 + tid;
        const int r = idx >> 2, c = idx & 3;
        const float* p = (const float*)Bw + (n0 + r) * (long)Kd + k0 + c * 8;
        const float4 f0 = *(const float4*)p;
        const float4 f1 = *(const float4*)(p + 4);
        u16x8 u;
        u[0] = f2bf(f0.x); u[1] = f2bf(f0.y); u[2] = f2bf(f0.z); u[3] = f2bf(f0.w);
        u[4] = f2bf(f1.x); u[5] = f2bf(f1.y); u[6] = f2bf(f1.z); u[7] = f2bf(f1.w);
        *(u16x8*)&smem[12288 + buf * 4096 + r * 32 + c * 8] = u;
      }
    }
  };

  // prologue: stage tiles 0 and 1
  stageA(0, 0);
  stageB(0, 0);
  if (nt > 1) {
    stageA(1, 32);
    stageB(1, 32);
  }

  for (int t = 0; t < nt; ++t) {
    if (!bF && t + 1 < nt) {
      // drain tile t's 4 loads; tile t+1's 4 stay in flight across barrier
      asm volatile("s_waitcnt vmcnt(4) lgkmcnt(0)\n\ts_barrier" ::: "memory");
    } else {
      asm volatile("s_waitcnt vmcnt(0) lgkmcnt(0)\n\ts_barrier" ::: "memory");
    }
    if (t + 2 < nt) {  // issue tile t+2; flies for TWO full iterations
      stageA((t + 2) % 3, (t + 2) << 5);
      stageB((t + 2) % 3, (t + 2) << 5);
    }
    const ushort_t* cA = smem + (t % 3) * 4096;
    const ushort_t* cB = smem + 12288 + (t % 3) * 4096;
    bf16x8 af[4], bfr[4];
#pragma unroll
    for (int i = 0; i < 4; ++i) {
      const int r = wm * 64 + i * 16 + l16;
      af[i] = ld_frag(&cA[r * 32 + quad * 8]);
    }
#pragma unroll
    for (int i = 0; i < 4; ++i) {
      const int r = wn * 64 + i * 16 + l16;
      bfr[i] = ld_frag(&cB[r * 32 + quad * 8]);
    }
#pragma unroll
    for (int i = 0; i < 4; ++i)
#pragma unroll
      for (int j = 0; j < 4; ++j) acc[i][j] = MFMA16(af[i], bfr[j], acc[i][j]);
  }

  // epilogue: C/D layout col=lane&15, row=quad*4+reg (m89-verified)
  if (EPI == 1 && (int)(n0 >> 10) == 2) {
    // V region: LDS transpose -> coalesced stores along tb.
    __syncthreads();  // all waves done with staging LDS
#pragma unroll
    for (int i = 0; i < 4; ++i) {
#pragma unroll
      for (int j = 0; j < 4; ++j) {
        const int nl = wn * 64 + j * 16 + l16;
        const int ml = wm * 64 + i * 16 + quad * 4;
        u16x4 pk;
#pragma unroll
        for (int reg = 0; reg < 4; ++reg) pk[reg] = f2bf(acc[i][j][reg]);
        *(u16x4*)&smem[nl * 136 + ml] = pk;  // stride 136: 16B-aligned rows
      }
    }
    __syncthreads();
    const long b = m0 >> 11;
    const long tb0 = m0 & 2047;
    const int h0 = (int)((n0 >> 6) & 15);
#pragma unroll
    for (int p = 0; p < 8; ++p) {
      const int nl = p * 16 + (tid >> 4);
      const int mc = (tid & 15) * 8;
      const u16x8 v = *(const u16x8*)&smem[nl * 136 + mc];
      const int h = h0 + (nl >> 6);
      const int d = nl & 63;
      *(u16x8*)&Vt[((b * 16 + h) * 64 + d) * 2048 + tb0 + mc] = v;
    }
    return;
  }
#pragma unroll
  for (int i = 0; i < 4; ++i) {
#pragma unroll
    for (int j = 0; j < 4; ++j) {
      if (EPI == 0) {
#pragma unroll
        for (int reg = 0; reg < 4; ++reg) {
          const long m = m0 + wm * 64 + i * 16 + quad * 4 + reg;
          const long n = n0 + wn * 64 + j * 16 + l16;
          C0[m * N + n] = acc[i][j][reg];
        }
      } else {
        const long n = n0 + wn * 64 + j * 16 + l16;
        const int h = (int)((n >> 6) & 15);
        const int d = (int)(n & 63);
        const long mbase = m0 + wm * 64 + i * 16 + quad * 4;
        const long b = mbase >> 11;
        const long tb = mbase & 2047;
        ushort_t* dst = ((int)(n >> 10) == 0) ? Qo : Ko;
#pragma unroll
        for (int reg = 0; reg < 4; ++reg)
          dst[((b * 16 + h) * 2048 + tb + reg) * 64 + d] = f2bf(acc[i][j][reg]);
      }
    }
  }
}

// ---------------------------------------------------------------------------
// Flash attention (causal), S^T/O^T formulation. R13-best version restored:
// unfused A/B jobs, gl2lds double-buffered K/V in swizzled-linear [64][64]
// LDS tiles, one barrier/iter, P roundtrip in swizzled 8KB region, Q direct
// from global. Swizzle: within-row byte ^= ((row&7)<<4); gl2lds writes
// linear so the global SOURCE is pre-swizzled (rule 21).
// ---------------------------------------------------------------------------

// softmax over S^T tile held in s[4] (keys = kb+nt*16+reg, q col = l16).
__device__ __forceinline__ void softmax_tile(f32x4* s, int kb, int qg, bool need_mask,
                                             float& m_i, float& l_i, f32x4* oacc) {
  float rmax = -1e30f;
  if (need_mask) {  // diagonal tiles only (wave-uniform)
#pragma unroll
    for (int nt = 0; nt < 4; ++nt) {
#pragma unroll
      for (int reg = 0; reg < 4; ++reg) {
        float v = s[nt][reg];
        if (kb + nt * 16 + reg > qg) v = -1e30f;
        s[nt][reg] = v;
        rmax = fmaxf(rmax, v);
      }
    }
  } else {
#pragma unroll
    for (int nt = 0; nt < 4; ++nt) {
#pragma unroll
      for (int reg = 0; reg < 4; ++reg) rmax = fmaxf(rmax, s[nt][reg]);
    }
  }
  rmax = fmaxf(rmax, __shfl_xor(rmax, 16, 64));
  rmax = fmaxf(rmax, __shfl_xor(rmax, 32, 64));
  float mnew = fmaxf(m_i, rmax);
  if (__all(rmax - m_i <= 5.5f)) {
    mnew = m_i;  // defer-max: P bounded by e^5.5 ~ 245, f32 accum tolerates
  } else {
    const float alpha = __expf(m_i - mnew);
    l_i *= alpha;
#pragma unroll
    for (int dt = 0; dt < 4; ++dt) oacc[dt] *= alpha;
    m_i = mnew;
  }
  float rs = 0.f;
#pragma unroll
  for (int nt = 0; nt < 4; ++nt) {
#pragma unroll
    for (int reg = 0; reg < 4; ++reg) {
      const float p = __expf(s[nt][reg] - mnew);
      s[nt][reg] = p;
      rs += p;
    }
  }
  rs += __shfl_xor(rs, 16, 64);
  rs += __shfl_xor(rs, 32, 64);
  l_i += rs;
}

// one q-tile job: QK^T -> softmax -> P roundtrip -> PV. sKc/sVc are the
// current swizzled [64][64] tiles; sPw is this wave's private P region.
__device__ __forceinline__ void attn_job(const bf16x8 qf[2], const ushort_t* sKc,
                                         const ushort_t* sVc, ushort_t* sPw,
                                         int kv, int qg, bool need_mask,
                                         int quad, int l8, int l16,
                                         float& m_i, float& l_i, f32x4* oacc) {
  const f32x4 ZERO4 = {0.f, 0.f, 0.f, 0.f};
  const int off0 = ((quad ^ l8) << 3);        // col16=quad   (kk=0), swizzled
  const int off1 = (((quad + 4) ^ l8) << 3);  // col16=quad+4 (kk=1), swizzled
  f32x4 s[4];
#pragma unroll
  for (int nt = 0; nt < 4; ++nt) {
    const ushort_t* krow = sKc + (nt * 16 + l16) * 64;
    s[nt] = MFMA16(ld_frag(krow + off0), qf[0], ZERO4);
    s[nt] = MFMA16(ld_frag(krow + off1), qf[1], s[nt]);
  }
  softmax_tile(s, kv * 64 + quad * 4, qg, need_mask, m_i, l_i, oacc);

  asm volatile("s_waitcnt lgkmcnt(0)" ::: "memory");  // WAR: prior sPw reads done
#pragma unroll
  for (int nt = 0; nt < 4; ++nt) {
    u16x4 pk;
#pragma unroll
    for (int reg = 0; reg < 4; ++reg) pk[reg] = f2bf(s[nt][reg]);
    // write elem (4*(4nt+quad)) ^ (l8<<3) of row l16 (swizzled, 8B-aligned)
    *(u16x4*)&sPw[l16 * 64 + (((4 * nt + quad) << 2) ^ (l8 << 3))] = pk;
  }
  asm volatile("s_waitcnt lgkmcnt(0)" ::: "memory");  // RAW: writes visible
  bf16x8 pf0 = ld_frag(&sPw[l16 * 64 + off0]);
  bf16x8 pf1 = ld_frag(&sPw[l16 * 64 + off1]);
#pragma unroll
  for (int dt = 0; dt < 4; ++dt) {
    const ushort_t* vrow = sVc + (dt * 16 + l16) * 64;
    oacc[dt] = MFMA16(ld_frag(vrow + off0), pf0, oacc[dt]);
    oacc[dt] = MFMA16(ld_frag(vrow + off1), pf1, oacc[dt]);
  }
}

__global__ __launch_bounds__(256, 4)
void attn_causal(const ushort_t* __restrict__ Qg, const ushort_t* __restrict__ Kg,
                 const ushort_t* __restrict__ Vt, ushort_t* __restrict__ Yg) {
  __shared__ ushort_t sK[2][64 * 64];  // swizzled-linear tiles, dbuf
  __shared__ ushort_t sV[2][64 * 64];
  __shared__ ushort_t sP[64 * 64];     // per-wave 16-row P regions
  const int tid = threadIdx.x;
  const int wave = tid >> 6, lane = tid & 63;
  const int quad = lane >> 4, l16 = lane & 15, l8 = lane & 7;
  const f32x4 ZERO4 = {0.f, 0.f, 0.f, 0.f};
  // XCD-aware bijective remap: XCD k owns bh in [8k,8k+8) -> 4MB KV = L2.
  const int lin = blockIdx.y * 16 + blockIdx.x;
  const int logical = (lin & 7) * 128 + (lin >> 3);
  const int qx = logical & 15, bh = logical >> 4;
  const int qtA = qx, qtB = 31 - qx;
  const size_t base = (size_t)bh * 2048 * 64;
  ushort_t* sPw = sP + wave * 16 * 64;

  // staging geometry: chunk = 8 rows x 128B; lane l -> row chunk*8+(l>>3),
  // LDS bytes (l&7)*16. Pre-swizzled SOURCE col: src col8 = (l&7) ^ ((l>>3)&7).
  const int srow = lane >> 3;                    // row within chunk
  const int scol = ((lane & 7) ^ srow) << 3;     // src col in elems (x8)

  // Q fragments direct from global, pre-scaled by 1/sqrt(64)=0.125 (exact)
  bf16x8 qfA[2], qfB[2];
#pragma unroll
  for (int tile = 0; tile < 2; ++tile) {
    const int qt = tile ? qtB : qtA;
    const size_t qrow = base + (size_t)(qt * 64 + wave * 16 + l16) * 64;
#pragma unroll
    for (int kk = 0; kk < 2; ++kk) {
      const u16x8 u = *(const u16x8*)(Qg + qrow + (kk * 4 + quad) * 8);
      u16x8 w;
#pragma unroll
      for (int e = 0; e < 8; ++e)
        w[e] = f2bf(__bfloat162float(__builtin_bit_cast(bf16, (ushort_t)u[e])) * 0.125f);
      const bf16x8 f = __builtin_bit_cast(bf16x8, w);
      if (tile) qfB[kk] = f; else qfA[kk] = f;
    }
  }

  float mA = -1e30f, lA = 0.f, mB = -1e30f, lB = 0.f;
  f32x4 oA[4], oB[4];
#pragma unroll
  for (int dt = 0; dt < 4; ++dt) {
    oA[dt] = ZERO4;
    oB[dt] = ZERO4;
  }
  const int qgA = qtA * 64 + wave * 16 + l16;
  const int qgB = qtB * 64 + wave * 16 + l16;
  const int qmA = qtA * 64 + wave * 16;  // wave-min q row (mask hoist)
  const int qmB = qtB * 64 + wave * 16;

  // prologue: stage tile 0 into buf 0 (async; drained by first barrier)
#pragma unroll
  for (int j = 0; j < 2; ++j) {
    const int chunk = wave * 2 + j;  // wave-uniform
    gl2lds16(Kg + base + (size_t)(chunk * 8 + srow) * 64 + scol,
             (char*)&sK[0][0] + chunk * 1024);
    gl2lds16(Vt + base + (size_t)(chunk * 8 + srow) * 2048 + scol,
             (char*)&sV[0][0] + chunk * 1024);
  }

  for (int kv = 0; kv <= qtB; ++kv) {
    const int cur = kv & 1;
    __syncthreads();  // drains vmcnt: buf[cur] filled; all waves past reads of buf[cur^1]
    if (kv < qtB) {   // async-stage tile kv+1 into the other buffer
      const int kn = kv + 1;
#pragma unroll
      for (int j = 0; j < 2; ++j) {
        const int chunk = wave * 2 + j;
        gl2lds16(Kg + base + (size_t)(kn * 64 + chunk * 8 + srow) * 64 + scol,
                 (char*)&sK[cur ^ 1][0] + chunk * 1024);
        gl2lds16(Vt + base + (size_t)(chunk * 8 + srow) * 2048 + kn * 64 + scol,
                 (char*)&sV[cur ^ 1][0] + chunk * 1024);
      }
    }
    const ushort_t* sKc = &sK[cur][0];
    const ushort_t* sVc = &sV[cur][0];
    attn_job(qfB, sKc, sVc, sPw, kv, qgB, kv * 64 + 63 > qmB, quad, l8, l16, mB, lB, oB);
    if (kv <= qtA)
      attn_job(qfA, sKc, sVc, sPw, kv, qgA, kv * 64 + 63 > qmA, quad, l8, l16, mA, lA, oA);
  }

  const int b = bh >> 4, h = bh & 15;
#pragma unroll
  for (int tile = 0; tile < 2; ++tile) {
    const int qt = tile ? qtB : qtA;
    const float linv = 1.f / (tile ? lB : lA);
    const f32x4* o = tile ? oB : oA;
    const int t = qt * 64 + wave * 16 + l16;
#pragma unroll
    for (int dt = 0; dt < 4; ++dt) {
      u16x4 pk;
#pragma unroll
      for (int reg = 0; reg < 4; ++reg) pk[reg] = f2bf(o[dt][reg] * linv);
      *(u16x4*)&Yg[(((size_t)b * 2048 + t) * 16 + h) * 64 + dt * 16 + quad * 4] = pk;
    }
  }
}

extern "C" void kernel_launch(void* const* d_in, const int* in_sizes, int n_in,
                              void* d_out, int out_size, void* d_ws, size_t ws_size,
                              hipStream_t stream) {
  const void* x = d_in[0];      // [4,2048,1024] fp32
  const void* w_qkv = d_in[1];  // [3072,1024] fp32
  const void* w_out = d_in[2];  // [1024,1024] fp32
  float* out = (float*)d_out;   // [4,2048,1024] fp32

  const size_t per = (size_t)4 * 16 * 2048 * 64;  // 8.39M elems
  const size_t nwqkv = (size_t)3072 * 1024;       // 3.15M
  const size_t nwout = (size_t)1024 * 1024;       // 1.05M
  ushort_t* qws = (ushort_t*)d_ws;   // [B,H,T,D]
  ushort_t* kws = qws + per;         // [B,H,T,D]
  ushort_t* vTws = kws + per;        // [B,H,D,T]
  ushort_t* xyws = vTws + per;       // xbf for gemm1, then y [B,T,H,D]
  ushort_t* wqkvb = xyws + per;      // bf16 w_qkv
  ushort_t* woutb = wqkvb + nwqkv;   // bf16 w_out
  int* flag = (int*)(woutb + nwout);
  const size_t need = (size_t)(4 * per + nwqkv + nwout) * 2 + 16;
  const bool pre = ws_size >= need;  // stable across calls (graph-safe)
  (void)in_sizes; (void)n_in; (void)out_size;

  dim3 blk(256);
  if (pre) {
    cvt_all<<<6144, 256, 0, stream>>>(x, w_qkv, w_out, xyws, wqkvb, woutb);
    gemm_nt<1><<<dim3(24, 64), blk, 0, stream>>>(xyws, wqkvb, flag, 0, nullptr,
                                                 qws, kws, vTws, 8192, 3072, 1024);
    attn_causal<<<dim3(16, 64), blk, 0, stream>>>(qws, kws, vTws, xyws);
    gemm_nt<0><<<dim3(8, 64), blk, 0, stream>>>(xyws, woutb, flag, 0, out,
                                                nullptr, nullptr, nullptr,
                                                8192, 1024, 1024);
  } else {
    flag = (int*)(xyws + per);
    detect_dtype<<<1, 256, 0, stream>>>((const ushort_t*)x, flag);
    cvt_all<<<4096, 256, 0, stream>>>(x, nullptr, nullptr, xyws, nullptr, nullptr);
    gemm_nt<1><<<dim3(24, 64), blk, 0, stream>>>(xyws, w_qkv, flag, 1, nullptr,
                                                 qws, kws, vTws, 8192, 3072, 1024);
    attn_causal<<<dim3(16, 64), blk, 0, stream>>>(qws, kws, vTws, xyws);
    gemm_nt<0><<<dim3(8, 64), blk, 0, stream>>>(xyws, w_out, flag, 1, out,
                                                nullptr, nullptr, nullptr,
                                                8192, 1024, 1024);
  }
}